// Round 23
// baseline (1278.436 us; speedup 1.0000x reference)
//
#include <hip/hip_runtime.h>
#include <hip/hip_bf16.h>

// Problem constants (match reference).
#define VOCAB  50257
#define D_EMB  128
#define HID    256
#define N_CLS  2
#define BSZ    256
#define T_LEN  2048

typedef float f16v __attribute__((ext_vector_type(16)));  // 16 f32 tuple
typedef float f2   __attribute__((ext_vector_type(2)));   // packed f32 pair

// ---------------------------------------------------------------------------
// Kernel 1: tab[v][j] = sum_d emb_table[v][d] * wx_w[d][j] + wx_b[j] + wh_b[j]
// ---------------------------------------------------------------------------
__global__ __launch_bounds__(256)
void tabax_kernel(const float* __restrict__ emb,
                  const float* __restrict__ wxw,
                  const float* __restrict__ wxb,
                  const float* __restrict__ whb,
                  float* __restrict__ tab)
{
    const int j  = threadIdx.x;          // output unit 0..255
    const int v0 = blockIdx.x * 32;
    const int rows = min(32, VOCAB - v0);

    __shared__ float ebuf[32 * D_EMB];   // 16 KB
    for (int i = j; i < rows * D_EMB; i += 256)
        ebuf[i] = emb[(size_t)v0 * D_EMB + i];
    __syncthreads();

    float acc[32];
#pragma unroll
    for (int r = 0; r < 32; ++r) acc[r] = 0.f;

#pragma unroll 8
    for (int d = 0; d < D_EMB; ++d) {
        float wxv = wxw[d * HID + j];    // coalesced
#pragma unroll
        for (int r = 0; r < 32; ++r)
            acc[r] = fmaf(ebuf[r * D_EMB + d], wxv, acc[r]); // LDS broadcast
    }

    const float bb = wxb[j] + whb[j];
    for (int r = 0; r < rows; ++r)
        tab[(size_t)(v0 + r) * HID + j] = acc[r] + bb;       // coalesced
}

// Fast tanh without IEEE division (R21 win): v_rcp is 1ulp.
__device__ __forceinline__ float fast_tanh(float x) {
    float e2 = __expf(2.f * x);
    float r  = __builtin_amdgcn_rcpf(e2 + 1.f);
    return fmaf(-2.f, r, 1.f);
}

// --- DPP reduce primitives (verified R18/R21) ---
#define DPP_ADD_ROR8(DST, SEND, KEEP)                                       \
    asm("v_add_f32 %0, %1, %2 row_ror:8 row_mask:0xf bank_mask:0xf"         \
        : "=v"(DST) : "v"(SEND), "v"(KEEP))
#define DPP_ADD_HMIR(DST, SEND, KEEP)                                       \
    asm("v_add_f32 %0, %1, %2 row_half_mirror row_mask:0xf bank_mask:0xf"   \
        : "=v"(DST) : "v"(SEND), "v"(KEEP))
#define DPP_QADD1(ACC)                                                      \
    asm("v_add_f32 %0, %0, %0 quad_perm:[1,0,3,2] row_mask:0xf "            \
        "bank_mask:0xf" : "+v"(ACC))
#define DPP_QADD2(ACC)                                                      \
    asm("v_add_f32 %0, %0, %0 quad_perm:[2,3,0,1] row_mask:0xf "            \
        "bank_mask:0xf" : "+v"(ACC))

// float2 pair (cols 2p, 2p+1) from tuple E at row m -- consecutive tuple
// elements = consecutive registers = a native pk operand pair.
#define WPAIR(E, M, P) ((f2){Wt[E][(M) * 4 + (P) * 2],                      \
                             Wt[E][(M) * 4 + (P) * 2 + 1]})

// ---------------------------------------------------------------------------
// Kernel 2 (main): one block per batch row, 1024 threads (16 waves, 4/SIMD).
// R22 base (1180us) with ONE change: the 64 scalar FMAs become 32
// compiler-generated v_pk_fma_f32 (float2 + __builtin_elementwise_fma).
// Unlike R14's hand-asm pk (tied "+v" chains, scheduler-defeating, -12%),
// source-level float2 leaves renaming/scheduling to the compiler; the
// {hm,hm} splat lowers to op_sel broadcast (no movs). Two 16-deep acc
// chains; at 4 waves/SIMD cross-wave issue hides chain latency.
// Everything else identical: tuple W, swizzled h reads (0 conflicts),
// 11-op DPP sel-pair reduce, rcp-tanh, x2 unroll, ax prefetch.
// ---------------------------------------------------------------------------
__global__ __launch_bounds__(1024, 1)
void rnn_main_kernel(const int*   __restrict__ batch,
                     const float* __restrict__ whw,
                     const float* __restrict__ clfw,
                     const float* __restrict__ clfb,
                     const float* __restrict__ ax_tab,
                     float*       __restrict__ out)
{
    const int b   = blockIdx.x;
    const int tid = threadIdx.x;
    const int kg  = tid & 15;            // k-group: k in [kg*16, kg*16+16)
    const int cg  = tid >> 4;            // col-group: cols [cg*4, cg*4+4)
    const int c0  = cg * 4;
    const int kb  = kg * 16;
    const int rot = (kg >> 2) & 3;       // bank-swizzle rotation

    __shared__ float hbuf[2][HID];       // double-buffered hidden state
    __shared__ float sbuf[2][HID];       // epilogue scratch

    // --- one-time weight load into 4 register tuples:
    // Wt[e][m*4+i] = wh_w[kb+((e+rot)&3)*4+m][c0+i]
    f16v Wt[4];
#pragma unroll
    for (int e = 0; e < 4; ++e) {
        const int swz = (e + rot) & 3;
#pragma unroll
        for (int m = 0; m < 4; ++m) {
            const int k = kb + swz * 4 + m;
            const float4 w4 = *(const float4*)&whw[(size_t)k * HID + c0];
            Wt[e][m * 4 + 0] = w4.x;
            Wt[e][m * 4 + 1] = w4.y;
            Wt[e][m * 4 + 2] = w4.z;
            Wt[e][m * 4 + 3] = w4.w;
        }
    }
    asm volatile("" : "+v"(Wt[0]));
    asm volatile("" : "+v"(Wt[1]));
    asm volatile("" : "+v"(Wt[2]));
    asm volatile("" : "+v"(Wt[3]));

    // LDS byte offsets of the 4 swizzled float4 reads (within one h buffer).
    int lds_off[4];
#pragma unroll
    for (int e = 0; e < 4; ++e) lds_off[e] = kg * 64 + ((e + rot) & 3) * 16;

    const int  mycol = c0 + (kg >> 2);   // column this lane's quad finalizes
    const bool wr    = (kg & 3) == 0;    // 1 lane per quad writes

    if (tid < HID) hbuf[0][tid] = 0.f;

    const int* brow = batch + (size_t)b * T_LEN;
    const float* axp = ax_tab + mycol;   // 32-bit offsets: tok*256 elems
    int tok_n = brow[0];
    float axv = axp[(unsigned)tok_n * 256u];           // ax for t=0
    tok_n = brow[1];
    __syncthreads();

#define RNN_STEP(CUR, NXT, TT)                                              \
    {                                                                       \
        const int tok_nn = ((TT) + 2 < T_LEN) ? brow[(TT) + 2] : 0;         \
        const float ax_n = axp[(unsigned)tok_n * 256u];                     \
        f2 acc01, acc23;                                                    \
        const char* hb = (const char*)&hbuf[CUR][0];                        \
        {   /* e = 0: m=0 initializes via packed mul */                     \
            const float4 h4 = *(const float4*)(hb + lds_off[0]);            \
            const f2 h0 = {h4.x, h4.x}, h1 = {h4.y, h4.y};                  \
            const f2 h2 = {h4.z, h4.z}, h3 = {h4.w, h4.w};                  \
            acc01 = h0 * WPAIR(0, 0, 0);                                    \
            acc23 = h0 * WPAIR(0, 0, 1);                                    \
            acc01 = __builtin_elementwise_fma(h1, WPAIR(0, 1, 0), acc01);   \
            acc23 = __builtin_elementwise_fma(h1, WPAIR(0, 1, 1), acc23);   \
            acc01 = __builtin_elementwise_fma(h2, WPAIR(0, 2, 0), acc01);   \
            acc23 = __builtin_elementwise_fma(h2, WPAIR(0, 2, 1), acc23);   \
            acc01 = __builtin_elementwise_fma(h3, WPAIR(0, 3, 0), acc01);   \
            acc23 = __builtin_elementwise_fma(h3, WPAIR(0, 3, 1), acc23);   \
        }                                                                   \
        _Pragma("unroll")                                                   \
        for (int e = 1; e < 4; ++e) {                                       \
            const float4 h4 = *(const float4*)(hb + lds_off[e]);            \
            const f2 h0 = {h4.x, h4.x}, h1 = {h4.y, h4.y};                  \
            const f2 h2 = {h4.z, h4.z}, h3 = {h4.w, h4.w};                  \
            acc01 = __builtin_elementwise_fma(h0, WPAIR(e, 0, 0), acc01);   \
            acc23 = __builtin_elementwise_fma(h0, WPAIR(e, 0, 1), acc23);   \
            acc01 = __builtin_elementwise_fma(h1, WPAIR(e, 1, 0), acc01);   \
            acc23 = __builtin_elementwise_fma(h1, WPAIR(e, 1, 1), acc23);   \
            acc01 = __builtin_elementwise_fma(h2, WPAIR(e, 2, 0), acc01);   \
            acc23 = __builtin_elementwise_fma(h2, WPAIR(e, 2, 1), acc23);   \
            acc01 = __builtin_elementwise_fma(h3, WPAIR(e, 3, 0), acc01);   \
            acc23 = __builtin_elementwise_fma(h3, WPAIR(e, 3, 1), acc23);   \
        }                                                                   \
        float acc[4] = {acc01.x, acc01.y, acc23.x, acc23.y};                \
        /* sel-pair reduce: L8 (ror8), acc 4 -> 2 */                        \
        const bool hi8 = (kg & 8) != 0;                                     \
        const float sA = hi8 ? acc[0] : acc[2];                             \
        const float kA = hi8 ? acc[2] : acc[0];                             \
        const float sB = hi8 ? acc[1] : acc[3];                             \
        const float kB = hi8 ? acc[3] : acc[1];                             \
        float accA, accB;                                                   \
        DPP_ADD_ROR8(accA, sA, kA);                                         \
        DPP_ADD_ROR8(accB, sB, kB);                                         \
        /* L4 (half-mirror, stays inside each 8-half), acc 2 -> 1 */        \
        const bool hi4 = (kg & 4) != 0;                                     \
        const float sC = hi4 ? accA : accB;                                 \
        const float kC = hi4 ? accB : accA;                                 \
        float accQ;                                                         \
        DPP_ADD_HMIR(accQ, sC, kC);                                         \
        /* quad levels: all 4 lanes of the quad end with the col total */   \
        DPP_QADD1(accQ);                                                    \
        DPP_QADD2(accQ);                                                    \
        const float hnew = fast_tanh(accQ + axv);                           \
        if (wr) hbuf[NXT][mycol] = hnew;                                    \
        __syncthreads();                                                    \
        axv   = ax_n;                                                       \
        tok_n = tok_nn;                                                     \
    }

    for (int t = 0; t < T_LEN; t += 2) {
        RNN_STEP(0, 1, t)
        RNN_STEP(1, 0, t + 1)
    }
#undef RNN_STEP

    // --- epilogue: out[b][c] = sum_j h[j] * clf_w[j][c] + clf_b[c] ---
    // After an even number of steps the final h is in hbuf[0].
    if (tid < HID) {
        const float h = hbuf[0][tid];
        sbuf[0][tid] = h * clfw[tid * N_CLS + 0];
        sbuf[1][tid] = h * clfw[tid * N_CLS + 1];
    }
    __syncthreads();
    if (tid < 64) {
        float v = sbuf[0][tid] + sbuf[0][tid + 64] +
                  sbuf[0][tid + 128] + sbuf[0][tid + 192];
#pragma unroll
        for (int off = 32; off > 0; off >>= 1) v += __shfl_xor(v, off);
        if (tid == 0) out[b * N_CLS + 0] = v + clfb[0];
    } else if (tid < 128) {
        const int l = tid - 64;
        float v = sbuf[1][l] + sbuf[1][l + 64] +
                  sbuf[1][l + 128] + sbuf[1][l + 192];
#pragma unroll
        for (int off = 32; off > 0; off >>= 1) v += __shfl_xor(v, off);
        if (l == 0) out[b * N_CLS + 1] = v + clfb[1];
    }
}

// ---------------------------------------------------------------------------
// Fallback (workspace too small for the 51.5 MB table).
// ---------------------------------------------------------------------------
__global__ __launch_bounds__(512, 2)
void rnn_fallback_kernel(const int*   __restrict__ batch,
                         const float* __restrict__ emb,
                         const float* __restrict__ wxw,
                         const float* __restrict__ wxb,
                         const float* __restrict__ whw,
                         const float* __restrict__ whb,
                         const float* __restrict__ clfw,
                         const float* __restrict__ clfb,
                         float*       __restrict__ out)
{
    const int b    = blockIdx.x;
    const int tid  = threadIdx.x;
    const int j    = tid >> 1;
    const int half = tid & 1;
    const int k0   = half * 128;

    __shared__ float hbuf[2][HID];
    __shared__ float ebuf[2][D_EMB];

    float w[128];
#pragma unroll
    for (int k = 0; k < 128; ++k)
        w[k] = whw[(size_t)(k0 + k) * HID + j];

    float wx[64];
#pragma unroll
    for (int d = 0; d < 64; ++d)
        wx[d] = wxw[(size_t)(half * 64 + d) * HID + j];

    const float bj  = whb[j];
    const float axb = wxb[j];

    if (tid < HID) hbuf[0][tid] = 0.f;

    const int* brow = batch + (size_t)b * T_LEN;

    int tok_n = brow[0];
    if (tid < D_EMB) ebuf[0][tid] = emb[(size_t)tok_n * D_EMB + tid];
    tok_n = brow[1];
    __syncthreads();

    float h_j = 0.f;
    int cur = 0;
    for (int t = 0; t < T_LEN; ++t) {
        const int nxt = cur ^ 1;
        const int tok_nn = (t + 2 < T_LEN) ? brow[t + 2] : 0;
        float ev = 0.f;
        if (t + 1 < T_LEN && tid < D_EMB)
            ev = emb[(size_t)tok_n * D_EMB + tid];

        float a0 = 0.f, a1 = 0.f, a2 = 0.f, a3 = 0.f;
        const float4* hv = (const float4*)&hbuf[cur][k0];
#pragma unroll
        for (int i = 0; i < 32; ++i) {
            float4 h4 = hv[i];
            a0 = fmaf(h4.x, w[4 * i + 0], a0);
            a1 = fmaf(h4.y, w[4 * i + 1], a1);
            a2 = fmaf(h4.z, w[4 * i + 2], a2);
            a3 = fmaf(h4.w, w[4 * i + 3], a3);
        }
        const float4* evv = (const float4*)&ebuf[cur][half * 64];
#pragma unroll
        for (int i = 0; i < 16; ++i) {
            float4 e4 = evv[i];
            a0 = fmaf(e4.x, wx[4 * i + 0], a0);
            a1 = fmaf(e4.y, wx[4 * i + 1], a1);
            a2 = fmaf(e4.z, wx[4 * i + 2], a2);
            a3 = fmaf(e4.w, wx[4 * i + 3], a3);
        }
        float s = (a0 + a1) + (a2 + a3);
        s += __shfl_xor(s, 1);

        h_j = fast_tanh(s + bj + axb);

        if (half == 0) hbuf[nxt][j] = h_j;
        if (t + 1 < T_LEN && tid < D_EMB) ebuf[nxt][tid] = ev;
        __syncthreads();

        tok_n = tok_nn;
        cur   = nxt;
    }

    if (half == 0) {
        hbuf[0][j] = h_j * clfw[j * N_CLS + 0];
        hbuf[1][j] = h_j * clfw[j * N_CLS + 1];
    }
    __syncthreads();
    if (tid < 64) {
        float v = hbuf[0][tid] + hbuf[0][tid + 64] +
                  hbuf[0][tid + 128] + hbuf[0][tid + 192];
#pragma unroll
        for (int off = 32; off > 0; off >>= 1) v += __shfl_xor(v, off);
        if (tid == 0) out[b * N_CLS + 0] = v + clfb[0];
    } else if (tid < 128) {
        const int l = tid - 64;
        float v = hbuf[1][l] + hbuf[1][l + 64] +
                  hbuf[1][l + 128] + hbuf[1][l + 192];
#pragma unroll
        for (int off = 32; off > 0; off >>= 1) v += __shfl_xor(v, off);
        if (l == 0) out[b * N_CLS + 1] = v + clfb[1];
    }
}

// ---------------------------------------------------------------------------
extern "C" void kernel_launch(void* const* d_in, const int* in_sizes, int n_in,
                              void* d_out, int out_size, void* d_ws, size_t ws_size,
                              hipStream_t stream)
{
    const int*   batch = (const int*)  d_in[0];
    const float* emb   = (const float*)d_in[1];
    const float* wxw   = (const float*)d_in[2];
    const float* wxb   = (const float*)d_in[3];
    const float* whw   = (const float*)d_in[4];
    const float* whb   = (const float*)d_in[5];
    const float* clfw  = (const float*)d_in[6];
    const float* clfb  = (const float*)d_in[7];
    float* out = (float*)d_out;

    const size_t tab_bytes = (size_t)VOCAB * HID * sizeof(float);
    if (ws_size >= tab_bytes) {
        float* tab = (float*)d_ws;
        tabax_kernel<<<(VOCAB + 31) / 32, 256, 0, stream>>>(emb, wxw, wxb, whb, tab);
        rnn_main_kernel<<<BSZ, 1024, 0, stream>>>(batch, whw, clfw, clfb, tab, out);
    } else {
        rnn_fallback_kernel<<<BSZ, 512, 0, stream>>>(batch, emb, wxw, wxb, whw, whb,
                                                     clfw, clfb, out);
    }
}

// Round 24
// 1178.353 us; speedup vs baseline: 1.0849x; 1.0849x over previous
//
#include <hip/hip_runtime.h>
#include <hip/hip_bf16.h>

// Problem constants (match reference).
#define VOCAB  50257
#define D_EMB  128
#define HID    256
#define N_CLS  2
#define BSZ    256
#define T_LEN  2048

typedef float f16v __attribute__((ext_vector_type(16)));  // 16 f32 tuple

// ---------------------------------------------------------------------------
// Kernel 1: tab[v][j] = sum_d emb_table[v][d] * wx_w[d][j] + wx_b[j] + wh_b[j]
// ---------------------------------------------------------------------------
__global__ __launch_bounds__(256)
void tabax_kernel(const float* __restrict__ emb,
                  const float* __restrict__ wxw,
                  const float* __restrict__ wxb,
                  const float* __restrict__ whb,
                  float* __restrict__ tab)
{
    const int j  = threadIdx.x;          // output unit 0..255
    const int v0 = blockIdx.x * 32;
    const int rows = min(32, VOCAB - v0);

    __shared__ float ebuf[32 * D_EMB];   // 16 KB
    for (int i = j; i < rows * D_EMB; i += 256)
        ebuf[i] = emb[(size_t)v0 * D_EMB + i];
    __syncthreads();

    float acc[32];
#pragma unroll
    for (int r = 0; r < 32; ++r) acc[r] = 0.f;

#pragma unroll 8
    for (int d = 0; d < D_EMB; ++d) {
        float wxv = wxw[d * HID + j];    // coalesced
#pragma unroll
        for (int r = 0; r < 32; ++r)
            acc[r] = fmaf(ebuf[r * D_EMB + d], wxv, acc[r]); // LDS broadcast
    }

    const float bb = wxb[j] + whb[j];
    for (int r = 0; r < rows; ++r)
        tab[(size_t)(v0 + r) * HID + j] = acc[r] + bb;       // coalesced
}

// Fast tanh without IEEE division (R21 win): v_rcp is 1ulp.
__device__ __forceinline__ float fast_tanh(float x) {
    float e2 = __expf(2.f * x);
    float r  = __builtin_amdgcn_rcpf(e2 + 1.f);
    return fmaf(-2.f, r, 1.f);
}

// --- DPP reduce primitives (verified R18/R21) ---
#define DPP_ADD_ROR8(DST, SEND, KEEP)                                       \
    asm("v_add_f32 %0, %1, %2 row_ror:8 row_mask:0xf bank_mask:0xf"         \
        : "=v"(DST) : "v"(SEND), "v"(KEEP))
#define DPP_ADD_HMIR(DST, SEND, KEEP)                                       \
    asm("v_add_f32 %0, %1, %2 row_half_mirror row_mask:0xf bank_mask:0xf"   \
        : "=v"(DST) : "v"(SEND), "v"(KEEP))
#define DPP_ADD_X2(DST, SEND, KEEP)                                         \
    asm("v_add_f32 %0, %1, %2 quad_perm:[2,3,0,1] row_mask:0xf "            \
        "bank_mask:0xf" : "=v"(DST) : "v"(SEND), "v"(KEEP))
#define DPP_QADD1(ACC)                                                      \
    asm("v_add_f32 %0, %0, %0 quad_perm:[1,0,3,2] row_mask:0xf "            \
        "bank_mask:0xf" : "+v"(ACC))

// ---------------------------------------------------------------------------
// Kernel 2 (main): one block per batch row, 512 threads (8 waves, 2/SIMD).
// THE EXPERIMENT: at 2 waves/SIMD the unified register budget is 256/wave,
// so the 128 weights/thread (+ ~50 working set) FIT in arch VGPRs with
// room to spare -- removing the AGPR-stash read tax (~64-128 insts/step)
// that capped every 4-wave variant (R7-R22; budget there was 128). R9's
// scalar-W version of this shape got stashed anyway, but R22 proved 16-wide
// TUPLES are the one lever that changes the allocator's choice. Decisive
// counter: VGPR_Count >= 160.
// Thread (cg = tid>>4 -> cols [cg*8, cg*8+8), kg = tid&15 -> k in
// [kg*16, +16)): 8 cols x 16 k = 128 W = 8 tuples. Swizzled h reads
// (rot=(kg>>2)&3, 0 conflicts measured). 8-col sel-pair DPP reduce
// (8 adds + 14 sels): L8 ror8 (8 accs->4, cols 0-3 low / 4-7 high),
// L4 half-mirror (4->2), L2 quad_perm xor2 (2->1), L1 quad_perm xor1.
// Col map: mycol = c0 + (kg>>3)*4 + ((kg>>2)&1) + (kg&2); writer kg&1==0.
// rcp-tanh, x2 time unroll, ax prefetch as R22.
// ---------------------------------------------------------------------------
__global__ __launch_bounds__(512, 1)
void rnn_main_kernel(const int*   __restrict__ batch,
                     const float* __restrict__ whw,
                     const float* __restrict__ clfw,
                     const float* __restrict__ clfb,
                     const float* __restrict__ ax_tab,
                     float*       __restrict__ out)
{
    const int b   = blockIdx.x;
    const int tid = threadIdx.x;
    const int kg  = tid & 15;            // k-group: k in [kg*16, kg*16+16)
    const int cg  = tid >> 4;            // col-group: cols [cg*8, cg*8+8)
    const int c0  = cg * 8;
    const int kb  = kg * 16;
    const int rot = (kg >> 2) & 3;       // bank-swizzle rotation

    __shared__ float hbuf[2][HID];       // double-buffered hidden state
    __shared__ float sbuf[2][HID];       // epilogue scratch

    // --- one-time weight load into 8 register tuples:
    // WtA[e][m*4+i] = W[k(e,m)][c0+i], WtB[e][m*4+i] = W[k(e,m)][c0+4+i],
    // k(e,m) = kb + ((e+rot)&3)*4 + m.
    f16v WtA[4], WtB[4];
#pragma unroll
    for (int e = 0; e < 4; ++e) {
        const int swz = (e + rot) & 3;
#pragma unroll
        for (int m = 0; m < 4; ++m) {
            const int k = kb + swz * 4 + m;
            const float4 wlo = *(const float4*)&whw[(size_t)k * HID + c0];
            const float4 whi = *(const float4*)&whw[(size_t)k * HID + c0 + 4];
            WtA[e][m * 4 + 0] = wlo.x; WtA[e][m * 4 + 1] = wlo.y;
            WtA[e][m * 4 + 2] = wlo.z; WtA[e][m * 4 + 3] = wlo.w;
            WtB[e][m * 4 + 0] = whi.x; WtB[e][m * 4 + 1] = whi.y;
            WtB[e][m * 4 + 2] = whi.z; WtB[e][m * 4 + 3] = whi.w;
        }
    }
    asm volatile("" : "+v"(WtA[0]));
    asm volatile("" : "+v"(WtA[1]));
    asm volatile("" : "+v"(WtA[2]));
    asm volatile("" : "+v"(WtA[3]));
    asm volatile("" : "+v"(WtB[0]));
    asm volatile("" : "+v"(WtB[1]));
    asm volatile("" : "+v"(WtB[2]));
    asm volatile("" : "+v"(WtB[3]));

    // LDS byte offsets of the 4 swizzled float4 reads (within one h buffer).
    int lds_off[4];
#pragma unroll
    for (int e = 0; e < 4; ++e) lds_off[e] = kg * 64 + ((e + rot) & 3) * 16;

    // Column this lane finalizes (see reduce derivation in header comment).
    const int  mycol = c0 + ((kg >> 3) << 2) + ((kg >> 2) & 1) + (kg & 2);
    const bool wr    = (kg & 1) == 0;    // 8 writers per 16-lane row

    if (tid < HID) hbuf[0][tid] = 0.f;

    const int* brow = batch + (size_t)b * T_LEN;
    const float* axp = ax_tab + mycol;   // 32-bit offsets: tok*256 elems
    int tok_n = brow[0];
    float axv = axp[(unsigned)tok_n * 256u];           // ax for t=0
    tok_n = brow[1];
    __syncthreads();

#define RNN_STEP(CUR, NXT, TT)                                              \
    {                                                                       \
        const int tok_nn = ((TT) + 2 < T_LEN) ? brow[(TT) + 2] : 0;         \
        const float ax_n = axp[(unsigned)tok_n * 256u];                     \
        float accA[4], accB[4];                                             \
        const char* hb = (const char*)&hbuf[CUR][0];                        \
        {   /* e = 0 initializes both chains */                             \
            const float4 h4 = *(const float4*)(hb + lds_off[0]);            \
            const float hm[4] = {h4.x, h4.y, h4.z, h4.w};                   \
            _Pragma("unroll")                                               \
            for (int i = 0; i < 4; ++i) {                                   \
                accA[i] = hm[0] * WtA[0][i];                                \
                accB[i] = hm[0] * WtB[0][i];                                \
            }                                                               \
            _Pragma("unroll")                                               \
            for (int m = 1; m < 4; ++m)                                     \
                _Pragma("unroll")                                           \
                for (int i = 0; i < 4; ++i) {                               \
                    accA[i] = fmaf(hm[m], WtA[0][m * 4 + i], accA[i]);      \
                    accB[i] = fmaf(hm[m], WtB[0][m * 4 + i], accB[i]);      \
                }                                                           \
        }                                                                   \
        _Pragma("unroll")                                                   \
        for (int e = 1; e < 4; ++e) {                                       \
            const float4 h4 = *(const float4*)(hb + lds_off[e]);            \
            const float hm[4] = {h4.x, h4.y, h4.z, h4.w};                   \
            _Pragma("unroll")                                               \
            for (int m = 0; m < 4; ++m)                                     \
                _Pragma("unroll")                                           \
                for (int i = 0; i < 4; ++i) {                               \
                    accA[i] = fmaf(hm[m], WtA[e][m * 4 + i], accA[i]);      \
                    accB[i] = fmaf(hm[m], WtB[e][m * 4 + i], accB[i]);      \
                }                                                           \
        }                                                                   \
        /* L8 (ror8): 8 accs -> 4. Low lanes keep cols 0-3, high 4-7. */    \
        const bool hi8 = (kg & 8) != 0;                                     \
        float P0, P1, P2, P3;                                               \
        {                                                                   \
            const float s0 = hi8 ? accA[0] : accB[0];                       \
            const float k0 = hi8 ? accB[0] : accA[0];                       \
            DPP_ADD_ROR8(P0, s0, k0);                                       \
            const float s1 = hi8 ? accA[1] : accB[1];                       \
            const float k1 = hi8 ? accB[1] : accA[1];                       \
            DPP_ADD_ROR8(P1, s1, k1);                                       \
            const float s2 = hi8 ? accA[2] : accB[2];                       \
            const float k2 = hi8 ? accB[2] : accA[2];                       \
            DPP_ADD_ROR8(P2, s2, k2);                                       \
            const float s3 = hi8 ? accA[3] : accB[3];                       \
            const float k3 = hi8 ? accB[3] : accA[3];                       \
            DPP_ADD_ROR8(P3, s3, k3);                                       \
        }                                                                   \
        /* L4 (half-mirror): 4 -> 2 */                                      \
        const bool hi4 = (kg & 4) != 0;                                     \
        float Q1, Q2;                                                       \
        {                                                                   \
            const float s1 = hi4 ? P0 : P1;                                 \
            const float k1 = hi4 ? P1 : P0;                                 \
            DPP_ADD_HMIR(Q1, s1, k1);                                       \
            const float s2 = hi4 ? P2 : P3;                                 \
            const float k2 = hi4 ? P3 : P2;                                 \
            DPP_ADD_HMIR(Q2, s2, k2);                                       \
        }                                                                   \
        /* L2 (quad xor2): 2 -> 1 */                                        \
        const bool hi2 = (kg & 2) != 0;                                     \
        float R;                                                            \
        {                                                                   \
            const float s = hi2 ? Q1 : Q2;                                  \
            const float k = hi2 ? Q2 : Q1;                                  \
            DPP_ADD_X2(R, s, k);                                            \
        }                                                                   \
        /* L1 (quad xor1): full 16-lane column sum */                       \
        DPP_QADD1(R);                                                       \
        const float hnew = fast_tanh(R + axv);                              \
        if (wr) hbuf[NXT][mycol] = hnew;                                    \
        __syncthreads();                                                    \
        axv   = ax_n;                                                       \
        tok_n = tok_nn;                                                     \
    }

    for (int t = 0; t < T_LEN; t += 2) {
        RNN_STEP(0, 1, t)
        RNN_STEP(1, 0, t + 1)
    }
#undef RNN_STEP

    // --- epilogue: out[b][c] = sum_j h[j] * clf_w[j][c] + clf_b[c] ---
    // After an even number of steps the final h is in hbuf[0].
    if (tid < HID) {
        const float h = hbuf[0][tid];
        sbuf[0][tid] = h * clfw[tid * N_CLS + 0];
        sbuf[1][tid] = h * clfw[tid * N_CLS + 1];
    }
    __syncthreads();
    if (tid < 64) {
        float v = sbuf[0][tid] + sbuf[0][tid + 64] +
                  sbuf[0][tid + 128] + sbuf[0][tid + 192];
#pragma unroll
        for (int off = 32; off > 0; off >>= 1) v += __shfl_xor(v, off);
        if (tid == 0) out[b * N_CLS + 0] = v + clfb[0];
    } else if (tid < 128) {
        const int l = tid - 64;
        float v = sbuf[1][l] + sbuf[1][l + 64] +
                  sbuf[1][l + 128] + sbuf[1][l + 192];
#pragma unroll
        for (int off = 32; off > 0; off >>= 1) v += __shfl_xor(v, off);
        if (l == 0) out[b * N_CLS + 1] = v + clfb[1];
    }
}

// ---------------------------------------------------------------------------
// Fallback (workspace too small for the 51.5 MB table).
// ---------------------------------------------------------------------------
__global__ __launch_bounds__(512, 2)
void rnn_fallback_kernel(const int*   __restrict__ batch,
                         const float* __restrict__ emb,
                         const float* __restrict__ wxw,
                         const float* __restrict__ wxb,
                         const float* __restrict__ whw,
                         const float* __restrict__ whb,
                         const float* __restrict__ clfw,
                         const float* __restrict__ clfb,
                         float*       __restrict__ out)
{
    const int b    = blockIdx.x;
    const int tid  = threadIdx.x;
    const int j    = tid >> 1;
    const int half = tid & 1;
    const int k0   = half * 128;

    __shared__ float hbuf[2][HID];
    __shared__ float ebuf[2][D_EMB];

    float w[128];
#pragma unroll
    for (int k = 0; k < 128; ++k)
        w[k] = whw[(size_t)(k0 + k) * HID + j];

    float wx[64];
#pragma unroll
    for (int d = 0; d < 64; ++d)
        wx[d] = wxw[(size_t)(half * 64 + d) * HID + j];

    const float bj  = whb[j];
    const float axb = wxb[j];

    if (tid < HID) hbuf[0][tid] = 0.f;

    const int* brow = batch + (size_t)b * T_LEN;

    int tok_n = brow[0];
    if (tid < D_EMB) ebuf[0][tid] = emb[(size_t)tok_n * D_EMB + tid];
    tok_n = brow[1];
    __syncthreads();

    float h_j = 0.f;
    int cur = 0;
    for (int t = 0; t < T_LEN; ++t) {
        const int nxt = cur ^ 1;
        const int tok_nn = (t + 2 < T_LEN) ? brow[t + 2] : 0;
        float ev = 0.f;
        if (t + 1 < T_LEN && tid < D_EMB)
            ev = emb[(size_t)tok_n * D_EMB + tid];

        float a0 = 0.f, a1 = 0.f, a2 = 0.f, a3 = 0.f;
        const float4* hv = (const float4*)&hbuf[cur][k0];
#pragma unroll
        for (int i = 0; i < 32; ++i) {
            float4 h4 = hv[i];
            a0 = fmaf(h4.x, w[4 * i + 0], a0);
            a1 = fmaf(h4.y, w[4 * i + 1], a1);
            a2 = fmaf(h4.z, w[4 * i + 2], a2);
            a3 = fmaf(h4.w, w[4 * i + 3], a3);
        }
        const float4* evv = (const float4*)&ebuf[cur][half * 64];
#pragma unroll
        for (int i = 0; i < 16; ++i) {
            float4 e4 = evv[i];
            a0 = fmaf(e4.x, wx[4 * i + 0], a0);
            a1 = fmaf(e4.y, wx[4 * i + 1], a1);
            a2 = fmaf(e4.z, wx[4 * i + 2], a2);
            a3 = fmaf(e4.w, wx[4 * i + 3], a3);
        }
        float s = (a0 + a1) + (a2 + a3);
        s += __shfl_xor(s, 1);

        h_j = fast_tanh(s + bj + axb);

        if (half == 0) hbuf[nxt][j] = h_j;
        if (t + 1 < T_LEN && tid < D_EMB) ebuf[nxt][tid] = ev;
        __syncthreads();

        tok_n = tok_nn;
        cur   = nxt;
    }

    if (half == 0) {
        hbuf[0][j] = h_j * clfw[j * N_CLS + 0];
        hbuf[1][j] = h_j * clfw[j * N_CLS + 1];
    }
    __syncthreads();
    if (tid < 64) {
        float v = hbuf[0][tid] + hbuf[0][tid + 64] +
                  hbuf[0][tid + 128] + hbuf[0][tid + 192];
#pragma unroll
        for (int off = 32; off > 0; off >>= 1) v += __shfl_xor(v, off);
        if (tid == 0) out[b * N_CLS + 0] = v + clfb[0];
    } else if (tid < 128) {
        const int l = tid - 64;
        float v = hbuf[1][l] + hbuf[1][l + 64] +
                  hbuf[1][l + 128] + hbuf[1][l + 192];
#pragma unroll
        for (int off = 32; off > 0; off >>= 1) v += __shfl_xor(v, off);
        if (l == 0) out[b * N_CLS + 1] = v + clfb[1];
    }
}

// ---------------------------------------------------------------------------
extern "C" void kernel_launch(void* const* d_in, const int* in_sizes, int n_in,
                              void* d_out, int out_size, void* d_ws, size_t ws_size,
                              hipStream_t stream)
{
    const int*   batch = (const int*)  d_in[0];
    const float* emb   = (const float*)d_in[1];
    const float* wxw   = (const float*)d_in[2];
    const float* wxb   = (const float*)d_in[3];
    const float* whw   = (const float*)d_in[4];
    const float* whb   = (const float*)d_in[5];
    const float* clfw  = (const float*)d_in[6];
    const float* clfb  = (const float*)d_in[7];
    float* out = (float*)d_out;

    const size_t tab_bytes = (size_t)VOCAB * HID * sizeof(float);
    if (ws_size >= tab_bytes) {
        float* tab = (float*)d_ws;
        tabax_kernel<<<(VOCAB + 31) / 32, 256, 0, stream>>>(emb, wxw, wxb, whb, tab);
        rnn_main_kernel<<<BSZ, 512, 0, stream>>>(batch, whw, clfw, clfb, tab, out);
    } else {
        rnn_fallback_kernel<<<BSZ, 512, 0, stream>>>(batch, emb, wxw, wxb, whw, whb,
                                                     clfw, clfb, out);
    }
}